// Round 2
// baseline (520.625 us; speedup 1.0000x reference)
//
#include <hip/hip_runtime.h>

// Problem: SphereConv2DEXP  — grid_sample(bilinear, zeros, align_corners=False)
// followed by 3x3 conv, stride 3  == implicit GEMM:
//   M = B*Ho*Wo = 4*128*256 = 131072,  N = Cout = 256,  K = Cin*9 = 1152
//
// R2: (a) K-step order = ci-block outer, ij inner  (ks -> ij = ks%9,
//     ci0 = (ks/9)*32). Single tap per step kept, but each 32-channel slab is
//     reused 9 consecutive steps -> L2-resident (fixes R1's 724 MB refetch).
//     (b) register-prefetch pipeline: x-taps/B-chunk/tap-weights for step ks+1
//     issued right after ds_writes of step ks, consumed next iteration; raw
//     s_barrier + lgkmcnt-only waits keep the loads in flight across barriers.

#define Hh   128
#define Ww   256
#define HWp  (Hh*Ww)        // 32768 per-channel image size
#define CIN  128
#define COUT 256
#define KTOT 1152
#define NPTS (384*768)      // 294912 grid points
#define BM   128
#define BN   256
#define BK   32
#define NKS  (KTOT/BK)      // 36 K-steps

typedef __attribute__((ext_vector_type(8))) __bf16 bf16x8;
typedef __attribute__((ext_vector_type(4))) float  f32x4;

// ---------------------------------------------------------------------------
// Kernel 1: bilinear tap table. For each grid point store:
//   tI = (row0*W + xb, row1*W + xb)   element offsets of two adjacent-column pairs
//   tW = weights for loaded positions (r0,xb),(r0,xb+1),(r1,xb),(r1,xb+1)
// ---------------------------------------------------------------------------
__global__ void build_table(const float* __restrict__ grid,
                            int2* __restrict__ tI, float4* __restrict__ tW) {
    int g = blockIdx.x * 256 + threadIdx.x;
    if (g >= NPTS) return;
    int hh = g / 768, ww = g - hh * 768;
    int ho = hh / 3, ii = hh - 3 * ho;
    int wo = ww / 3, jj = ww - 3 * wo;

    float gx = grid[2 * g + 0];
    float gy = grid[2 * g + 1];
    float ix = ((gx + 1.0f) * (float)Ww - 1.0f) * 0.5f;
    float iy = ((gy + 1.0f) * (float)Hh - 1.0f) * 0.5f;
    float x0f = floorf(ix), y0f = floorf(iy);
    int x0 = (int)x0f, y0 = (int)y0f;
    float wx1 = ix - x0f, wx0 = 1.0f - wx1;
    float wy1 = iy - y0f, wy0 = 1.0f - wy1;

    float wyt = (y0 >= 0 && y0 < Hh) ? wy0 : 0.0f;
    float wyb = (y0 + 1 >= 0 && y0 + 1 < Hh) ? wy1 : 0.0f;
    int r0 = min(max(y0, 0), Hh - 1);
    int r1 = min(max(y0 + 1, 0), Hh - 1);

    int xb; float cw0, cw1;
    if (x0 < 0)            { xb = 0;      cw0 = wx1; cw1 = 0.0f; }
    else if (x0 > Ww - 2)  { xb = Ww - 2; cw0 = 0.0f; cw1 = wx0; }
    else                   { xb = x0;     cw0 = wx0; cw1 = wx1; }

    int e = (ho * Ww + wo) * 9 + ii * 3 + jj;   // (sp, ij) order
    tI[e] = make_int2(r0 * Ww + xb, r1 * Ww + xb);
    tW[e] = make_float4(cw0 * wyt, cw1 * wyt, cw0 * wyb, cw1 * wyb);
}

// ---------------------------------------------------------------------------
// Kernel 2: weight f32 -> bf16, retiled as wt[ks][n][kk] with the PERMUTED
// K order: step ks -> ij = ks%9, ci = (ks/9)*32 + kk.
// ---------------------------------------------------------------------------
__global__ void conv_w(const float* __restrict__ w, __bf16* __restrict__ wt) {
    int o = blockIdx.x * 256 + threadIdx.x;   // over NKS*COUT*BK = 294912
    if (o >= NKS * COUT * BK) return;
    int kk = o & (BK - 1);
    int n  = (o >> 5) & (COUT - 1);
    int ks = o >> 13;
    int ij = ks % 9;
    int ci = (ks / 9) * 32 + kk;
    wt[o] = (__bf16)w[n * KTOT + ci * 9 + ij];
}

// ---------------------------------------------------------------------------
// Kernel 3: fused gather + bf16 MFMA GEMM, register-prefetch pipelined.
// Block: 512 thr (8 waves, 2x4), tile BM=128 x BN=256, K-step 32.
// Step ks: ij = ks%9 (fixed), channels (ks/9)*32 .. +31.
// ---------------------------------------------------------------------------
__global__ __launch_bounds__(512, 4) void sphconv_gemm(
    const float* __restrict__ x, const __bf16* __restrict__ wt,
    const float* __restrict__ bias, const int2* __restrict__ tI,
    const float4* __restrict__ tW, float* __restrict__ out) {

    __shared__ int2   sTI[BM * 9];
    __shared__ float4 sTW[BM * 9];
    __shared__ __align__(16) __bf16 sA[BM * 40];
    __shared__ __align__(16) __bf16 sB[BN * 40];

    const int t   = threadIdx.x;
    const int m0  = blockIdx.x * BM;
    const int b   = m0 >> 15;           // / 32768
    const int sp0 = m0 & (HWp - 1);
    const float* xb_ = x + (size_t)b * (CIN * HWp);

    for (int e = t; e < BM * 9; e += 512) {
        sTI[e] = tI[sp0 * 9 + e];
        sTW[e] = tW[sp0 * 9 + e];
    }

    const int lane = t & 63;
    const int wid  = t >> 6;
    const int wrow = wid >> 2;          // 0..1 -> m offset 64*wrow
    const int wcol = wid & 3;           // 0..3 -> n offset 64*wcol
    const int quad = lane >> 4;         // 0..3
    const int l16  = lane & 15;

    const int mr_s = t & 127;           // staging row (fixed sp per thread)
    const int kg   = t >> 7;            // 0..3 -> kk base = 8*kg
    const int wn   = t >> 1;            // B staging row
    const int wkq  = (t & 1) * 16;

    f32x4 acc[4][4];
#pragma unroll
    for (int r = 0; r < 4; ++r)
#pragma unroll
        for (int c = 0; c < 4; ++c) {
            f32x4 z = {0.0f, 0.0f, 0.0f, 0.0f};
            acc[r][c] = z;
        }

    __syncthreads();  // table ready

    // ---- prologue: prefetch step 0 into registers ----
    float2 px[8], py[8];      // two row-pairs per channel, 8 channels
    bf16x8 pb0, pb1;          // B chunk
    float4 wv;                // tap weights for the current step
    {
        const int2 o = sTI[mr_s * 9 + 0];
        wv = sTW[mr_s * 9 + 0];
        const float* img = xb_ + (size_t)(kg * 8) * HWp;
#pragma unroll
        for (int j = 0; j < 8; ++j) {
            px[j] = *(const float2*)(img + o.x);
            py[j] = *(const float2*)(img + o.y);
            img += HWp;
        }
        const __bf16* src = wt + t * 16;
        pb0 = *(const bf16x8*)(src);
        pb1 = *(const bf16x8*)(src + 8);
    }

    int ij = 0, cb = 0;
    for (int ks = 0; ks < NKS; ++ks) {
        // ---- consume prefetched x: weighted gather -> bf16, stage A ----
        bf16x8 av;
#pragma unroll
        for (int j = 0; j < 8; ++j)
            av[j] = (__bf16)(px[j].x * wv.x + px[j].y * wv.y +
                             py[j].x * wv.z + py[j].y * wv.w);
        *(bf16x8*)(&sA[mr_s * 40 + kg * 8]) = av;

        // ---- stage B from prefetched regs ----
        *(bf16x8*)(&sB[wn * 40 + wkq])     = pb0;
        *(bf16x8*)(&sB[wn * 40 + wkq + 8]) = pb1;

        // ---- issue prefetch for step ks+1 (stays in flight across barriers) ----
        int ij2 = ij + 1, cb2 = cb;
        if (ij2 == 9) { ij2 = 0; cb2 += 32; }
        if (ks + 1 < NKS) {
            const int2 o = sTI[mr_s * 9 + ij2];
            wv = sTW[mr_s * 9 + ij2];
            const float* img = xb_ + (size_t)(cb2 + kg * 8) * HWp;
#pragma unroll
            for (int j = 0; j < 8; ++j) {
                px[j] = *(const float2*)(img + o.x);
                py[j] = *(const float2*)(img + o.y);
                img += HWp;
            }
            const __bf16* src = wt + (ks + 1) * (COUT * BK) + t * 16;
            pb0 = *(const bf16x8*)(src);
            pb1 = *(const bf16x8*)(src + 8);
        }
        ij = ij2; cb = cb2;

        // LDS writes visible to all waves; global reg-loads stay in flight
        asm volatile("s_waitcnt lgkmcnt(0)" ::: "memory");
        __builtin_amdgcn_s_barrier();

        // ---- fragments + 16 MFMA ----
        bf16x8 af[4], bfr[4];
#pragma unroll
        for (int r = 0; r < 4; ++r)
            af[r] = *(const bf16x8*)(&sA[(wrow * 64 + r * 16 + l16) * 40 + quad * 8]);
#pragma unroll
        for (int c = 0; c < 4; ++c)
            bfr[c] = *(const bf16x8*)(&sB[(wcol * 64 + c * 16 + l16) * 40 + quad * 8]);
#pragma unroll
        for (int r = 0; r < 4; ++r)
#pragma unroll
            for (int c = 0; c < 4; ++c)
                acc[r][c] = __builtin_amdgcn_mfma_f32_16x16x32_bf16(
                    af[r], bfr[c], acc[r][c], 0, 0, 0);

        // all waves done reading frags before next iteration's ds_writes
        asm volatile("s_waitcnt lgkmcnt(0)" ::: "memory");
        __builtin_amdgcn_s_barrier();
    }

    // ---- epilogue: D row=(quad*4+i), col=(lane&15)  [m89-verified layout] ----
#pragma unroll
    for (int c = 0; c < 4; ++c) {
        int n = wcol * 64 + c * 16 + l16;
        float bv = bias[n];
        float* outn = out + (((size_t)(b * COUT + n)) << 15) + sp0;
#pragma unroll
        for (int r = 0; r < 4; ++r) {
            int mbase = wrow * 64 + r * 16 + quad * 4;
            float4 v = make_float4(acc[r][c][0] + bv, acc[r][c][1] + bv,
                                   acc[r][c][2] + bv, acc[r][c][3] + bv);
            *(float4*)(&outn[mbase]) = v;   // 16B aligned
        }
    }
}

// ---------------------------------------------------------------------------
extern "C" void kernel_launch(void* const* d_in, const int* in_sizes, int n_in,
                              void* d_out, int out_size, void* d_ws, size_t ws_size,
                              hipStream_t stream) {
    const float* x    = (const float*)d_in[0];
    const float* w    = (const float*)d_in[1];
    const float* bias = (const float*)d_in[2];
    const float* grid = (const float*)d_in[3];
    float* out = (float*)d_out;

    char* ws = (char*)d_ws;
    int2*   tI = (int2*)(ws);                       // 294912 * 8  = 2359296 B
    float4* tW = (float4*)(ws + 2359296);           // 294912 * 16 = 4718592 B
    __bf16* wt = (__bf16*)(ws + 7077888);           // 294912 * 2  =  589824 B

    build_table<<<(NPTS + 255) / 256, 256, 0, stream>>>(grid, tI, tW);
    conv_w<<<(NKS * COUT * BK + 255) / 256, 256, 0, stream>>>(w, wt);
    sphconv_gemm<<<(4 * HWp) / BM, 512, 0, stream>>>(x, wt, bias, tI, tW, out);
}

// Round 3
// 396.354 us; speedup vs baseline: 1.3135x; 1.3135x over previous
//
#include <hip/hip_runtime.h>

// Problem: SphereConv2DEXP  — grid_sample(bilinear, zeros, align_corners=False)
// followed by 3x3 conv, stride 3  == implicit GEMM:
//   M = B*Ho*Wo = 4*128*256 = 131072,  N = Cout = 256,  K = Cin*9 = 1152
//
// R3: R2's ci-outer/ij-inner K order (L2 locality) kept, but the pipeline is
// restructured to fit the 128-VGPR budget (R2 spilled: WRITE_SIZE 131->434 MB):
//   - wave tile 32x64 (BM=64): acc 64->32 VGPRs, gather 32->16 in-flight VGPRs
//   - double-buffered LDS, ONE __syncthreads per K-step; next-step loads are
//     issued before the current step's MFMA and consumed after it (same iter,
//     no cross-barrier register holding -> no lgkmcnt asm games, no spill)
//   - prep kernels merged into one launch

#define Hh   128
#define Ww   256
#define HWp  (Hh*Ww)        // 32768 per-channel image size
#define CIN  128
#define COUT 256
#define KTOT 1152
#define NPTS (384*768)      // 294912 grid points
#define BM   64
#define BN   256
#define BK   32
#define NKS  (KTOT/BK)      // 36 K-steps

typedef __attribute__((ext_vector_type(8))) __bf16 bf16x8;
typedef __attribute__((ext_vector_type(4))) __bf16 bf16x4;
typedef __attribute__((ext_vector_type(4))) float  f32x4;

// ---------------------------------------------------------------------------
// Prep kernel (merged): blocks [0,1152) build the bilinear tap table,
// blocks [1152,2304) convert/retile the conv weights.
//   tI = (row0*W + xb, row1*W + xb), tW = weights for the 4 loaded positions.
//   wt[ks][n][kk] in PERMUTED K order: step ks -> ij = ks%9, ci = (ks/9)*32+kk.
// ---------------------------------------------------------------------------
__global__ void prep(const float* __restrict__ grid, const float* __restrict__ w,
                     int2* __restrict__ tI, float4* __restrict__ tW,
                     __bf16* __restrict__ wt) {
    if (blockIdx.x < NPTS / 256) {
        int g = blockIdx.x * 256 + threadIdx.x;
        int hh = g / 768, ww = g - hh * 768;
        int ho = hh / 3, ii = hh - 3 * ho;
        int wo = ww / 3, jj = ww - 3 * wo;

        float gx = grid[2 * g + 0];
        float gy = grid[2 * g + 1];
        float ix = ((gx + 1.0f) * (float)Ww - 1.0f) * 0.5f;
        float iy = ((gy + 1.0f) * (float)Hh - 1.0f) * 0.5f;
        float x0f = floorf(ix), y0f = floorf(iy);
        int x0 = (int)x0f, y0 = (int)y0f;
        float wx1 = ix - x0f, wx0 = 1.0f - wx1;
        float wy1 = iy - y0f, wy0 = 1.0f - wy1;

        float wyt = (y0 >= 0 && y0 < Hh) ? wy0 : 0.0f;
        float wyb = (y0 + 1 >= 0 && y0 + 1 < Hh) ? wy1 : 0.0f;
        int r0 = min(max(y0, 0), Hh - 1);
        int r1 = min(max(y0 + 1, 0), Hh - 1);

        int xb; float cw0, cw1;
        if (x0 < 0)            { xb = 0;      cw0 = wx1; cw1 = 0.0f; }
        else if (x0 > Ww - 2)  { xb = Ww - 2; cw0 = 0.0f; cw1 = wx0; }
        else                   { xb = x0;     cw0 = wx0; cw1 = wx1; }

        int e = (ho * Ww + wo) * 9 + ii * 3 + jj;   // (sp, ij) order
        tI[e] = make_int2(r0 * Ww + xb, r1 * Ww + xb);
        tW[e] = make_float4(cw0 * wyt, cw1 * wyt, cw0 * wyb, cw1 * wyb);
    } else {
        int o = (blockIdx.x - NPTS / 256) * 256 + threadIdx.x;  // NKS*COUT*BK
        int kk = o & (BK - 1);
        int n  = (o >> 5) & (COUT - 1);
        int ks = o >> 13;
        int ij = ks % 9;
        int ci = (ks / 9) * 32 + kk;
        wt[o] = (__bf16)w[n * KTOT + ci * 9 + ij];
    }
}

// ---------------------------------------------------------------------------
// Fused gather + bf16 MFMA GEMM, double-buffered, one barrier per K-step.
// Block: 512 thr (8 waves, 2x4), tile BM=64 x BN=256, K-step 32.
// Wave tile 32x64 = 2x4 frags of mfma_f32_16x16x32_bf16 (acc = 32 VGPR).
// Step ks: ij = ks%9 (fixed), channels (ks/9)*32 .. +31.
// A staging: thread t -> row (t&63), channels kg*4..kg*4+3 (kg = t>>6).
// ---------------------------------------------------------------------------
__global__ __launch_bounds__(512, 4) void sphconv_gemm(
    const float* __restrict__ x, const __bf16* __restrict__ wt,
    const float* __restrict__ bias, const int2* __restrict__ tI,
    const float4* __restrict__ tW, float* __restrict__ out) {

    __shared__ int2   sTI[BM * 9];                       //  4608 B
    __shared__ float4 sTW[BM * 9];                       //  9216 B
    __shared__ __align__(16) __bf16 sA[2][BM * 40];      // 2x 5120 B
    __shared__ __align__(16) __bf16 sB[2][BN * 40];      // 2x20480 B  -> 65024 total

    const int t   = threadIdx.x;
    const int m0  = blockIdx.x * BM;
    const int b   = m0 >> 15;           // / 32768
    const int sp0 = m0 & (HWp - 1);
    const float* xb_ = x + (size_t)b * (CIN * HWp);

    for (int e = t; e < BM * 9; e += 512) {
        sTI[e] = tI[sp0 * 9 + e];
        sTW[e] = tW[sp0 * 9 + e];
    }

    const int lane = t & 63;
    const int wid  = t >> 6;
    const int wrow = wid >> 2;          // 0..1 -> m offset 32*wrow
    const int wcol = wid & 3;           // 0..3 -> n offset 64*wcol
    const int quad = lane >> 4;         // 0..3
    const int l16  = lane & 15;

    const int mr_s = t & 63;            // staging row (fixed sp per thread)
    const int kg   = t >> 6;            // 0..7 -> kk base = 4*kg
    const int wn   = t >> 1;            // B staging row
    const int wkq  = (t & 1) * 16;

    f32x4 acc[2][4];
#pragma unroll
    for (int r = 0; r < 2; ++r)
#pragma unroll
        for (int c = 0; c < 4; ++c) {
            f32x4 z = {0.0f, 0.0f, 0.0f, 0.0f};
            acc[r][c] = z;
        }

    __syncthreads();  // table ready

    // ---- prologue: stage step 0 into buffer 0 ----
    {
        const int2   o  = sTI[mr_s * 9 + 0];
        const float4 wv = sTW[mr_s * 9 + 0];
        const float* img = xb_ + (size_t)(kg * 4) * HWp;
        bf16x4 av;
#pragma unroll
        for (int j = 0; j < 4; ++j) {
            float2 p0 = *(const float2*)(img + o.x);
            float2 p1 = *(const float2*)(img + o.y);
            av[j] = (__bf16)(p0.x * wv.x + p0.y * wv.y + p1.x * wv.z + p1.y * wv.w);
            img += HWp;
        }
        *(bf16x4*)(&sA[0][mr_s * 40 + kg * 4]) = av;
        const __bf16* src = wt + t * 16;
        *(bf16x8*)(&sB[0][wn * 40 + wkq])     = *(const bf16x8*)(src);
        *(bf16x8*)(&sB[0][wn * 40 + wkq + 8]) = *(const bf16x8*)(src + 8);
    }
    __syncthreads();  // buffer 0 ready

    int ij = 0, cb = 0;
    for (int ks = 0; ks < NKS; ++ks) {
        const int cur = ks & 1, nxt = cur ^ 1;

        // ---- issue next-step loads FIRST (hidden under current MFMA) ----
        float2 qx[4], qy[4];
        bf16x8 pb0, pb1;
        float4 wv2;
        const bool have = (ks + 1 < NKS);
        int ij2 = (ij == 8) ? 0 : ij + 1;
        int cb2 = (ij == 8) ? cb + 32 : cb;
        if (have) {
            const int2 o = sTI[mr_s * 9 + ij2];
            wv2 = sTW[mr_s * 9 + ij2];
            const float* img = xb_ + (size_t)(cb2 + kg * 4) * HWp;
#pragma unroll
            for (int j = 0; j < 4; ++j) {
                qx[j] = *(const float2*)(img + o.x);
                qy[j] = *(const float2*)(img + o.y);
                img += HWp;
            }
            const __bf16* src = wt + (ks + 1) * (COUT * BK) + t * 16;
            pb0 = *(const bf16x8*)(src);
            pb1 = *(const bf16x8*)(src + 8);
        }

        // ---- current step: fragments + 8 MFMA (independent of the loads) ----
        bf16x8 af[2], bfr[4];
#pragma unroll
        for (int r = 0; r < 2; ++r)
            af[r] = *(const bf16x8*)(&sA[cur][(wrow * 32 + r * 16 + l16) * 40 + quad * 8]);
#pragma unroll
        for (int c = 0; c < 4; ++c)
            bfr[c] = *(const bf16x8*)(&sB[cur][(wcol * 64 + c * 16 + l16) * 40 + quad * 8]);
#pragma unroll
        for (int r = 0; r < 2; ++r)
#pragma unroll
            for (int c = 0; c < 4; ++c)
                acc[r][c] = __builtin_amdgcn_mfma_f32_16x16x32_bf16(
                    af[r], bfr[c], acc[r][c], 0, 0, 0);

        // ---- consume loads, stage buffers for step ks+1 ----
        if (have) {
            bf16x4 av;
#pragma unroll
            for (int j = 0; j < 4; ++j)
                av[j] = (__bf16)(qx[j].x * wv2.x + qx[j].y * wv2.y +
                                 qy[j].x * wv2.z + qy[j].y * wv2.w);
            *(bf16x4*)(&sA[nxt][mr_s * 40 + kg * 4]) = av;
            *(bf16x8*)(&sB[nxt][wn * 40 + wkq])     = pb0;
            *(bf16x8*)(&sB[nxt][wn * 40 + wkq + 8]) = pb1;
        }

        __syncthreads();   // nxt staged for everyone; cur reads all complete
        ij = ij2; cb = cb2;
    }

    // ---- epilogue: D row=(quad*4+i), col=(lane&15)  [m89-verified layout] ----
#pragma unroll
    for (int c = 0; c < 4; ++c) {
        int n = wcol * 64 + c * 16 + l16;
        float bv = bias[n];
        float* outn = out + (((size_t)(b * COUT + n)) << 15) + sp0;
#pragma unroll
        for (int r = 0; r < 2; ++r) {
            int mbase = wrow * 32 + r * 16 + quad * 4;
            float4 v = make_float4(acc[r][c][0] + bv, acc[r][c][1] + bv,
                                   acc[r][c][2] + bv, acc[r][c][3] + bv);
            *(float4*)(&outn[mbase]) = v;   // 16B aligned
        }
    }
}

// ---------------------------------------------------------------------------
extern "C" void kernel_launch(void* const* d_in, const int* in_sizes, int n_in,
                              void* d_out, int out_size, void* d_ws, size_t ws_size,
                              hipStream_t stream) {
    const float* x    = (const float*)d_in[0];
    const float* w    = (const float*)d_in[1];
    const float* bias = (const float*)d_in[2];
    const float* grid = (const float*)d_in[3];
    float* out = (float*)d_out;

    char* ws = (char*)d_ws;
    int2*   tI = (int2*)(ws);                       // 294912 * 8  = 2359296 B
    float4* tW = (float4*)(ws + 2359296);           // 294912 * 16 = 4718592 B
    __bf16* wt = (__bf16*)(ws + 7077888);           // 294912 * 2  =  589824 B

    prep<<<NPTS / 256 + (NKS * COUT * BK) / 256, 256, 0, stream>>>(grid, w, tI, tW, wt);
    sphconv_gemm<<<(4 * HWp) / BM, 512, 0, stream>>>(x, wt, bias, tI, tW, out);
}